// Round 7
// baseline (149.546 us; speedup 1.0000x reference)
//
#include <hip/hip_runtime.h>
#include <hip/hip_bf16.h>

#define N_PTS 65536
#define LOG2E 1.4426950408889634f
#define INV2PI 0.15915494309189535f

typedef __attribute__((ext_vector_type(8))) short short8;
typedef __attribute__((ext_vector_type(4))) short short4v;
typedef __attribute__((ext_vector_type(4))) float float4v;

#if __has_builtin(__builtin_amdgcn_exp2f)
#define EXP2F(x) __builtin_amdgcn_exp2f(x)
#else
#define EXP2F(x) exp2f(x)
#endif

// cos with argument in revolutions (weights pre-scaled by 1/2pi in prep).
#if __has_builtin(__builtin_amdgcn_cosf) && __has_builtin(__builtin_amdgcn_fractf)
#define COS_REV(v) __builtin_amdgcn_cosf(__builtin_amdgcn_fractf(v))
#else
#define COS_REV(v) __cosf((v) * 6.283185307179586f)
#endif

__device__ __forceinline__ short f2b(float f) {
    __hip_bfloat16 h = __float2bfloat16(f);
    return *(short*)&h;
}
__device__ __forceinline__ float b2f(short s) {
    __hip_bfloat16 h = *(__hip_bfloat16*)&s;
    return __bfloat162float(h);
}

// ---------------- prep (layout identical to R5/R6) ----------------
//   zb   [1024][16] bf16 @ 0        bf16(log2e * z)
//   FbB  [512][16] bf16  @ 32768    FbB[o*64+l][i] = bf16(F[o][i][l] / 2pi)
//   BWd  [64][512] bf16  @ 49152    block-diag sqrt(2/64)*pw
//   Wtb  [64][1024] bf16 @ 114688   bf16(W)
//   z2h  [1024] f32      @ 245760   0.5*log2e*||bf16(z_m)||^2
//   phs  [512] f32       @ 249856   ph / 2pi
__global__ __launch_bounds__(256) void prep_kernel(
    const float* __restrict__ z, const float* __restrict__ W,
    const float* __restrict__ F, const float* __restrict__ pw,
    const float* __restrict__ ph,
    short* __restrict__ zb, short* __restrict__ FbB,
    short* __restrict__ BWd, short* __restrict__ Wtb,
    float* __restrict__ z2h, float* __restrict__ phs)
{
    int t = blockIdx.x * 256 + threadIdx.x;
    if (t < 16384) {
        zb[t] = f2b(LOG2E * z[t]);
    } else if (t < 17408) {
        int m = t - 16384;
        const float4v* zp = (const float4v*)(z + (size_t)m * 16);
        float s = 0.f;
        #pragma unroll
        for (int k = 0; k < 4; k++) {
            float4v v = zp[k];
            float a0 = b2f(f2b(v.x)), a1 = b2f(f2b(v.y));
            float a2 = b2f(f2b(v.z)), a3 = b2f(f2b(v.w));
            s += a0 * a0 + a1 * a1 + a2 * a2 + a3 * a3;
        }
        z2h[m] = 0.5f * LOG2E * s;
    } else if (t < 25600) {
        int p = t - 17408;
        int o = p >> 10, l = (p >> 4) & 63, i = p & 15;
        FbB[p] = f2b(INV2PI * F[o * 1024 + i * 64 + l]);
    } else if (t < 58368) {
        int p = t - 25600;
        int so = p >> 9, ol = p & 511, o = ol >> 6;
        float v = ((so & 7) == o) ? 0.17677669529663687f * pw[so * 64 + (ol & 63)] : 0.f;
        BWd[p] = f2b(v);
    } else if (t < 123904) {
        int p = t - 58368;
        Wtb[p] = f2b(W[p]);
    } else if (t < 124416) {
        int p = t - 123904;
        phs[p] = INV2PI * ph[p];
    }
}

// ---------------- fused prior + data ----------------
// Identical structure to R6 EXCEPT __launch_bounds__(256, 6):
// R6's (256,8) capped VGPR at 64 -> compiler allocated 32 + scratch spill
// (WRITE_SIZE 51 MB vs 16.4 MB output). Cap 85 fits the ~60-70 live values
// -> no spill, still up to 6 blocks/CU (75% occupancy) vs R2's 4.
// 256 thr (4 waves), n-block 32, grid 2048. Single tile 32x132 bf16 (8.7 KB
// LDS), 2 barriers/chunk. Tile row stride 132 shorts: measured 0 conflicts.
// Production: wave w -> row half rw=w&1, col half hp=w>>1.
// GEMM: wave w -> so-strip 16w, both n-tiles.
__global__ __launch_bounds__(256, 6) void fused_kernel(
    const float* __restrict__ x,
    const short* __restrict__ zb, const short* __restrict__ FbB,
    const short* __restrict__ BWd, const short* __restrict__ Wtb,
    const float* __restrict__ z2h, const float* __restrict__ phs,
    float* __restrict__ out)
{
    __shared__ __align__(16) short tile[32 * 132];
    __shared__ float x2c[32];

    const int tid = threadIdx.x;
    const int lane = tid & 63, w = tid >> 6;
    const int q = lane >> 4, c = lane & 15;
    const int rw = w & 1, hp = w >> 1;
    const int n0 = blockIdx.x * 32;

    if (tid < 32) {
        float s = 0.f;
        const float4v* xr = (const float4v*)(x + (size_t)(n0 + tid) * 16);
        #pragma unroll
        for (int k = 0; k < 4; k++) {
            float4v v = xr[k];
            float a0 = b2f(f2b(v.x)), a1 = b2f(f2b(v.y));
            float a2 = b2f(f2b(v.z)), a3 = b2f(f2b(v.w));
            s += a0 * a0 + a1 * a1 + a2 * a2 + a3 * a3;
        }
        x2c[tid] = 0.5f * LOG2E * s;
    }

    // x A-fragment for production row half rw (K=16 real, quads 2,3 zero)
    short8 ax = (short8)0;
    if (q < 2) {
        const float4v* xp = (const float4v*)(x + (size_t)(n0 + 16 * rw + c) * 16 + q * 8);
        float4v v0 = xp[0], v1 = xp[1];
        ax[0] = f2b(v0.x); ax[1] = f2b(v0.y); ax[2] = f2b(v0.z); ax[3] = f2b(v0.w);
        ax[4] = f2b(v1.x); ax[5] = f2b(v1.y); ax[6] = f2b(v1.z); ax[7] = f2b(v1.w);
    }

    float4v acc[2];
    acc[0] = (float4v)(0.f);
    acc[1] = (float4v)(0.f);

    __syncthreads();

    float mx2[4];
    #pragma unroll
    for (int r = 0; r < 4; r++) mx2[r] = -x2c[16 * rw + 4 * q + r];

    // ===== prior: cos((x.F + ph) / 2pi rev) @ blockdiag(pws), 4 chunks of 128 =====
    #pragma unroll
    for (int p = 0; p < 4; p++) {
        #pragma unroll
        for (int lt = 0; lt < 4; lt++) {
            const int f = p * 128 + hp * 64 + lt * 16 + c;
            short8 bf = (short8)0;
            if (q < 2) bf = *(const short8*)(FbB + (f * 16 + q * 8));
            float phv = phs[f];
            float4v c0 = {phv, phv, phv, phv};
            float4v d = __builtin_amdgcn_mfma_f32_16x16x32_bf16(ax, bf, c0, 0, 0, 0);
            #pragma unroll
            for (int r = 0; r < 4; r++)
                tile[(16 * rw + 4 * q + r) * 132 + hp * 64 + lt * 16 + c] = f2b(COS_REV(d[r]));
        }
        short8 aw[4];
        #pragma unroll
        for (int ks = 0; ks < 4; ks++)
            aw[ks] = *(const short8*)(BWd + ((16 * w + c) * 512 + p * 128 + ks * 32 + q * 8));
        __syncthreads();
        #pragma unroll
        for (int ks = 0; ks < 4; ks++) {
            #pragma unroll
            for (int nt = 0; nt < 2; nt++) {
                const short* tp = tile + (nt * 16 + c) * 132 + ks * 32 + q * 8;
                short4v lo = *(const short4v*)tp;
                short4v hi = *(const short4v*)(tp + 4);
                short8 bb = __builtin_shufflevector(lo, hi, 0, 1, 2, 3, 4, 5, 6, 7);
                acc[nt] = __builtin_amdgcn_mfma_f32_16x16x32_bf16(aw[ks], bb, acc[nt], 0, 0, 0);
            }
        }
        __syncthreads();
    }

    // ===== data: exp2(log2e*(dot - (x2+z2)/2)) @ W^T, 8 chunks of 128 =====
    #pragma unroll
    for (int mc = 0; mc < 8; mc++) {
        #pragma unroll
        for (int mt = 0; mt < 4; mt++) {
            const int m = mc * 128 + hp * 64 + mt * 16 + c;
            short8 bz = (short8)0;
            if (q < 2) bz = *(const short8*)(zb + (m * 16 + q * 8));
            float z2v = z2h[m];
            float4v c0;
            #pragma unroll
            for (int r = 0; r < 4; r++) c0[r] = mx2[r] - z2v;
            float4v d = __builtin_amdgcn_mfma_f32_16x16x32_bf16(ax, bz, c0, 0, 0, 0);
            #pragma unroll
            for (int r = 0; r < 4; r++)
                tile[(16 * rw + 4 * q + r) * 132 + hp * 64 + mt * 16 + c] = f2b(EXP2F(d[r]));
        }
        short8 aw[4];
        #pragma unroll
        for (int ks = 0; ks < 4; ks++)
            aw[ks] = *(const short8*)(Wtb + ((16 * w + c) * 1024 + mc * 128 + ks * 32 + q * 8));
        __syncthreads();
        #pragma unroll
        for (int ks = 0; ks < 4; ks++) {
            #pragma unroll
            for (int nt = 0; nt < 2; nt++) {
                const short* tp = tile + (nt * 16 + c) * 132 + ks * 32 + q * 8;
                short4v lo = *(const short4v*)tp;
                short4v hi = *(const short4v*)(tp + 4);
                short8 bb = __builtin_shufflevector(lo, hi, 0, 1, 2, 3, 4, 5, 6, 7);
                acc[nt] = __builtin_amdgcn_mfma_f32_16x16x32_bf16(aw[ks], bb, acc[nt], 0, 0, 0);
            }
        }
        __syncthreads();
    }

    // epilogue: D[row=q*4+r -> so=16w+..][col=c -> n], n-tiles 0,1
    #pragma unroll
    for (int nt = 0; nt < 2; nt++) {
        #pragma unroll
        for (int r = 0; r < 4; r++) {
            out[(size_t)(16 * w + 4 * q + r) * N_PTS + n0 + nt * 16 + c] = acc[nt][r];
        }
    }
}

extern "C" void kernel_launch(void* const* d_in, const int* in_sizes, int n_in,
                              void* d_out, int out_size, void* d_ws, size_t ws_size,
                              hipStream_t stream) {
    const float* x  = (const float*)d_in[0];   // [65536][16]
    const float* z  = (const float*)d_in[1];   // [1024][16]
    const float* W  = (const float*)d_in[2];   // [8][8][1024] = [64][1024]
    const float* F  = (const float*)d_in[3];   // [8][16][64]
    const float* ph = (const float*)d_in[4];   // [8][64]
    const float* pw = (const float*)d_in[5];   // [8][8][64] = [64][64]
    float* out = (float*)d_out;                // [64][65536]

    char* ws = (char*)d_ws;
    short* zb  = (short*)(ws);            // 32768 B
    short* FbB = (short*)(ws + 32768);    // 16384 B
    short* BWd = (short*)(ws + 49152);    // 65536 B
    short* Wtb = (short*)(ws + 114688);   // 131072 B
    float* z2h = (float*)(ws + 245760);   // 4096 B
    float* phs = (float*)(ws + 249856);   // 2048 B

    prep_kernel<<<486, 256, 0, stream>>>(z, W, F, pw, ph, zb, FbB, BWd, Wtb, z2h, phs);
    fused_kernel<<<2048, 256, 0, stream>>>(x, zb, FbB, BWd, Wtb, z2h, phs, out);
}

// Round 8
// 139.593 us; speedup vs baseline: 1.0713x; 1.0713x over previous
//
#include <hip/hip_runtime.h>
#include <hip/hip_bf16.h>

#define N_PTS 65536
#define LOG2E 1.4426950408889634f
#define INV2PI 0.15915494309189535f

typedef __attribute__((ext_vector_type(8))) short short8;
typedef __attribute__((ext_vector_type(4))) short short4v;
typedef __attribute__((ext_vector_type(4))) float float4v;

#if __has_builtin(__builtin_amdgcn_exp2f)
#define EXP2F(x) __builtin_amdgcn_exp2f(x)
#else
#define EXP2F(x) exp2f(x)
#endif

// cos with argument in revolutions (weights pre-scaled by 1/2pi in prep).
#if __has_builtin(__builtin_amdgcn_cosf) && __has_builtin(__builtin_amdgcn_fractf)
#define COS_REV(v) __builtin_amdgcn_cosf(__builtin_amdgcn_fractf(v))
#else
#define COS_REV(v) __cosf((v) * 6.283185307179586f)
#endif

__device__ __forceinline__ short f2b(float f) {
    __hip_bfloat16 h = __float2bfloat16(f);
    return *(short*)&h;
}
__device__ __forceinline__ float b2f(short s) {
    __hip_bfloat16 h = *(__hip_bfloat16*)&s;
    return __bfloat162float(h);
}

// ---------------- prep (layout identical to R5/R6/R7) ----------------
//   zb   [1024][16] bf16 @ 0        bf16(log2e * z)
//   FbB  [512][16] bf16  @ 32768    FbB[o*64+l][i] = bf16(F[o][i][l] / 2pi)
//   BWd  [64][512] bf16  @ 49152    block-diag sqrt(2/64)*pw
//   Wtb  [64][1024] bf16 @ 114688   bf16(W)
//   z2h  [1024] f32      @ 245760   0.5*log2e*||bf16(z_m)||^2
//   phs  [512] f32       @ 249856   ph / 2pi
__global__ __launch_bounds__(256) void prep_kernel(
    const float* __restrict__ z, const float* __restrict__ W,
    const float* __restrict__ F, const float* __restrict__ pw,
    const float* __restrict__ ph,
    short* __restrict__ zb, short* __restrict__ FbB,
    short* __restrict__ BWd, short* __restrict__ Wtb,
    float* __restrict__ z2h, float* __restrict__ phs)
{
    int t = blockIdx.x * 256 + threadIdx.x;
    if (t < 16384) {
        zb[t] = f2b(LOG2E * z[t]);
    } else if (t < 17408) {
        int m = t - 16384;
        const float4v* zp = (const float4v*)(z + (size_t)m * 16);
        float s = 0.f;
        #pragma unroll
        for (int k = 0; k < 4; k++) {
            float4v v = zp[k];
            float a0 = b2f(f2b(v.x)), a1 = b2f(f2b(v.y));
            float a2 = b2f(f2b(v.z)), a3 = b2f(f2b(v.w));
            s += a0 * a0 + a1 * a1 + a2 * a2 + a3 * a3;
        }
        z2h[m] = 0.5f * LOG2E * s;
    } else if (t < 25600) {
        int p = t - 17408;
        int o = p >> 10, l = (p >> 4) & 63, i = p & 15;
        FbB[p] = f2b(INV2PI * F[o * 1024 + i * 64 + l]);
    } else if (t < 58368) {
        int p = t - 25600;
        int so = p >> 9, ol = p & 511, o = ol >> 6;
        float v = ((so & 7) == o) ? 0.17677669529663687f * pw[so * 64 + (ol & 63)] : 0.f;
        BWd[p] = f2b(v);
    } else if (t < 123904) {
        int p = t - 58368;
        Wtb[p] = f2b(W[p]);
    } else if (t < 124416) {
        int p = t - 123904;
        phs[p] = INV2PI * ph[p];
    }
}

// ---------------- fused prior + data ----------------
// Identical to R6/R7 EXCEPT __launch_bounds__(256, 4).
// Evidence: bounds (256,8) -> VGPR 32 + 35 MB spill writes (R6); (256,6) ->
// VGPR 40 + 18 MB spill writes, occ 46% (R7); (256,4) historically -> VGPR
// ~52, WRITE exactly 16384 KB (R2/R3). With n-block 32 / grid 2048 / 8.7 KB
// LDS, runtime occupancy is grid-limited at 8 blocks/CU x 4 waves = 32
// waves/CU — no launch_bounds pressure needed.
// 256 thr (4 waves). Single tile 32x132 bf16, 2 barriers/chunk.
// Tile row stride 132 shorts: measured 0 conflicts (R5-R7).
// Production: wave w -> row half rw=w&1, col half hp=w>>1.
// GEMM: wave w -> so-strip 16w, both n-tiles.
__global__ __launch_bounds__(256, 4) void fused_kernel(
    const float* __restrict__ x,
    const short* __restrict__ zb, const short* __restrict__ FbB,
    const short* __restrict__ BWd, const short* __restrict__ Wtb,
    const float* __restrict__ z2h, const float* __restrict__ phs,
    float* __restrict__ out)
{
    __shared__ __align__(16) short tile[32 * 132];
    __shared__ float x2c[32];

    const int tid = threadIdx.x;
    const int lane = tid & 63, w = tid >> 6;
    const int q = lane >> 4, c = lane & 15;
    const int rw = w & 1, hp = w >> 1;
    const int n0 = blockIdx.x * 32;

    if (tid < 32) {
        float s = 0.f;
        const float4v* xr = (const float4v*)(x + (size_t)(n0 + tid) * 16);
        #pragma unroll
        for (int k = 0; k < 4; k++) {
            float4v v = xr[k];
            float a0 = b2f(f2b(v.x)), a1 = b2f(f2b(v.y));
            float a2 = b2f(f2b(v.z)), a3 = b2f(f2b(v.w));
            s += a0 * a0 + a1 * a1 + a2 * a2 + a3 * a3;
        }
        x2c[tid] = 0.5f * LOG2E * s;
    }

    // x A-fragment for production row half rw (K=16 real, quads 2,3 zero)
    short8 ax = (short8)0;
    if (q < 2) {
        const float4v* xp = (const float4v*)(x + (size_t)(n0 + 16 * rw + c) * 16 + q * 8);
        float4v v0 = xp[0], v1 = xp[1];
        ax[0] = f2b(v0.x); ax[1] = f2b(v0.y); ax[2] = f2b(v0.z); ax[3] = f2b(v0.w);
        ax[4] = f2b(v1.x); ax[5] = f2b(v1.y); ax[6] = f2b(v1.z); ax[7] = f2b(v1.w);
    }

    float4v acc[2];
    acc[0] = (float4v)(0.f);
    acc[1] = (float4v)(0.f);

    __syncthreads();

    float mx2[4];
    #pragma unroll
    for (int r = 0; r < 4; r++) mx2[r] = -x2c[16 * rw + 4 * q + r];

    // ===== prior: cos((x.F + ph) / 2pi rev) @ blockdiag(pws), 4 chunks of 128 =====
    #pragma unroll
    for (int p = 0; p < 4; p++) {
        #pragma unroll
        for (int lt = 0; lt < 4; lt++) {
            const int f = p * 128 + hp * 64 + lt * 16 + c;
            short8 bf = (short8)0;
            if (q < 2) bf = *(const short8*)(FbB + (f * 16 + q * 8));
            float phv = phs[f];
            float4v c0 = {phv, phv, phv, phv};
            float4v d = __builtin_amdgcn_mfma_f32_16x16x32_bf16(ax, bf, c0, 0, 0, 0);
            #pragma unroll
            for (int r = 0; r < 4; r++)
                tile[(16 * rw + 4 * q + r) * 132 + hp * 64 + lt * 16 + c] = f2b(COS_REV(d[r]));
        }
        short8 aw[4];
        #pragma unroll
        for (int ks = 0; ks < 4; ks++)
            aw[ks] = *(const short8*)(BWd + ((16 * w + c) * 512 + p * 128 + ks * 32 + q * 8));
        __syncthreads();
        #pragma unroll
        for (int ks = 0; ks < 4; ks++) {
            #pragma unroll
            for (int nt = 0; nt < 2; nt++) {
                const short* tp = tile + (nt * 16 + c) * 132 + ks * 32 + q * 8;
                short4v lo = *(const short4v*)tp;
                short4v hi = *(const short4v*)(tp + 4);
                short8 bb = __builtin_shufflevector(lo, hi, 0, 1, 2, 3, 4, 5, 6, 7);
                acc[nt] = __builtin_amdgcn_mfma_f32_16x16x32_bf16(aw[ks], bb, acc[nt], 0, 0, 0);
            }
        }
        __syncthreads();
    }

    // ===== data: exp2(log2e*(dot - (x2+z2)/2)) @ W^T, 8 chunks of 128 =====
    #pragma unroll
    for (int mc = 0; mc < 8; mc++) {
        #pragma unroll
        for (int mt = 0; mt < 4; mt++) {
            const int m = mc * 128 + hp * 64 + mt * 16 + c;
            short8 bz = (short8)0;
            if (q < 2) bz = *(const short8*)(zb + (m * 16 + q * 8));
            float z2v = z2h[m];
            float4v c0;
            #pragma unroll
            for (int r = 0; r < 4; r++) c0[r] = mx2[r] - z2v;
            float4v d = __builtin_amdgcn_mfma_f32_16x16x32_bf16(ax, bz, c0, 0, 0, 0);
            #pragma unroll
            for (int r = 0; r < 4; r++)
                tile[(16 * rw + 4 * q + r) * 132 + hp * 64 + mt * 16 + c] = f2b(EXP2F(d[r]));
        }
        short8 aw[4];
        #pragma unroll
        for (int ks = 0; ks < 4; ks++)
            aw[ks] = *(const short8*)(Wtb + ((16 * w + c) * 1024 + mc * 128 + ks * 32 + q * 8));
        __syncthreads();
        #pragma unroll
        for (int ks = 0; ks < 4; ks++) {
            #pragma unroll
            for (int nt = 0; nt < 2; nt++) {
                const short* tp = tile + (nt * 16 + c) * 132 + ks * 32 + q * 8;
                short4v lo = *(const short4v*)tp;
                short4v hi = *(const short4v*)(tp + 4);
                short8 bb = __builtin_shufflevector(lo, hi, 0, 1, 2, 3, 4, 5, 6, 7);
                acc[nt] = __builtin_amdgcn_mfma_f32_16x16x32_bf16(aw[ks], bb, acc[nt], 0, 0, 0);
            }
        }
        __syncthreads();
    }

    // epilogue: D[row=q*4+r -> so=16w+..][col=c -> n], n-tiles 0,1
    #pragma unroll
    for (int nt = 0; nt < 2; nt++) {
        #pragma unroll
        for (int r = 0; r < 4; r++) {
            out[(size_t)(16 * w + 4 * q + r) * N_PTS + n0 + nt * 16 + c] = acc[nt][r];
        }
    }
}

extern "C" void kernel_launch(void* const* d_in, const int* in_sizes, int n_in,
                              void* d_out, int out_size, void* d_ws, size_t ws_size,
                              hipStream_t stream) {
    const float* x  = (const float*)d_in[0];   // [65536][16]
    const float* z  = (const float*)d_in[1];   // [1024][16]
    const float* W  = (const float*)d_in[2];   // [8][8][1024] = [64][1024]
    const float* F  = (const float*)d_in[3];   // [8][16][64]
    const float* ph = (const float*)d_in[4];   // [8][64]
    const float* pw = (const float*)d_in[5];   // [8][8][64] = [64][64]
    float* out = (float*)d_out;                // [64][65536]

    char* ws = (char*)d_ws;
    short* zb  = (short*)(ws);            // 32768 B
    short* FbB = (short*)(ws + 32768);    // 16384 B
    short* BWd = (short*)(ws + 49152);    // 65536 B
    short* Wtb = (short*)(ws + 114688);   // 131072 B
    float* z2h = (float*)(ws + 245760);   // 4096 B
    float* phs = (float*)(ws + 249856);   // 2048 B

    prep_kernel<<<486, 256, 0, stream>>>(z, W, F, pw, ph, zb, FbB, BWd, Wtb, z2h, phs);
    fused_kernel<<<2048, 256, 0, stream>>>(x, zb, FbB, BWd, Wtb, z2h, phs, out);
}